// Round 7
// baseline (985.722 us; speedup 1.0000x reference)
//
#include <hip/hip_runtime.h>
#include <hip/hip_bf16.h>

#define NN 50000   // nodes
#define NE 400000  // edges
#define DD 384     // input dim
#define HC 512     // heads * per-head dim (4 heads x 128)

typedef unsigned int u32;
typedef unsigned short u16;
typedef __attribute__((ext_vector_type(8))) short bf16x8;  // 8 bf16 (4 VGPRs)
typedef __attribute__((ext_vector_type(4))) float f32x4;

#define AS1 __attribute__((address_space(1)))
#define AS3 __attribute__((address_space(3)))

__device__ __forceinline__ float bflo(u32 u){ return __uint_as_float(u << 16); }
__device__ __forceinline__ float bfhi(u32 u){ return __uint_as_float(u & 0xFFFF0000u); }
__device__ __forceinline__ u16 f2bf(float f){
    u32 u = __float_as_uint(f);
    return (u16)((u + 0x7FFFu + ((u >> 16) & 1u)) >> 16);   // RNE
}
__device__ __forceinline__ u32 pack2(float a, float b){
    return (u32)f2bf(a) | ((u32)f2bf(b) << 16);
}

// ---------------------------------------------------------------------------
// 2-deep pipelined MFMA GEMM: Y[n,O] = A[n,K]*W[O,K]^T + bias, all-bf16 in.
// 128x128 tile, BK=64, 4 waves 2x2, LDS [2][128][128B] per operand (64 KB).
// Counted vmcnt: stage(t+1)/(t+2) stay in flight across raw s_barriers —
// vmcnt(8) waits only the oldest stage (8 gload_lds/thread/stage).
// Per iter: vmcnt(8); barrier; ds_read+MFMA; barrier; issue stage(t+2).
// XOR-swizzled 16B chunks (chunk ^= row&7) on both stage-source and read.
// 1D grid, bijective XCD swizzle, col-tile fastest within XCD (L2 A-reuse).
// ---------------------------------------------------------------------------
template<int K, bool QKVS>
__global__ __launch_bounds__(256)
void gemm2ph(const u16* __restrict__ Ab, const u16* __restrict__ Wb,
             const float* __restrict__ bias,
             u16* __restrict__ oQ, u16* __restrict__ oK,
             u16* __restrict__ oV, u16* __restrict__ oS,
             float* __restrict__ oF, int n, int Ototal, int NT)
{
    constexpr int NKT = K / 64;
    __shared__ char smA[2][16384];     // [buf][128 rows][128 B]
    __shared__ char smB[2][16384];

    // ---- bijective XCD swizzle ----
    const int nb  = gridDim.x;
    const int bd  = blockIdx.x;
    const int q8  = nb >> 3, r8 = nb & 7;
    const int xcd = bd & 7, gg = bd >> 3;
    const int tt  = (xcd < r8 ? xcd * (q8 + 1) : r8 * (q8 + 1) + (xcd - r8) * q8) + gg;
    const int m0  = (tt / NT) * 128;
    const int o0  = (tt % NT) * 128;

    const int tid  = threadIdx.x;
    const int lane = tid & 63;
    const int w    = tid >> 6;
    const int wr   = w >> 1, wc = w & 1;
    const int r16  = lane & 15;
    const int kq   = lane >> 4;
    const int swz  = (r16 & 7) << 4;

    // 8 gload_lds per call (4 B-chunks then 4 A-chunks) -> vmcnt unit = 8
    auto stage = [&](int bf, int kt) {
        #pragma unroll
        for (int p = 0; p < 4; ++p) {
            int ci = p * 256 + tid, row = ci >> 3, pc = ci & 7;
            int lc = pc ^ (row & 7);
            const u16* g = Wb + (size_t)(o0 + row) * K + kt * 64 + lc * 8;
            __builtin_amdgcn_global_load_lds((const AS1 u32*)g,
                                             (AS3 u32*)(smB[bf] + ci * 16), 16, 0, 0);
        }
        #pragma unroll
        for (int p = 0; p < 4; ++p) {
            int ci = p * 256 + tid, row = ci >> 3, pc = ci & 7;
            int lc = pc ^ (row & 7);
            int gr = m0 + row; if (gr >= n) gr = n - 1;
            const u16* g = Ab + (size_t)gr * K + kt * 64 + lc * 8;
            __builtin_amdgcn_global_load_lds((const AS1 u32*)g,
                                             (AS3 u32*)(smA[bf] + ci * 16), 16, 0, 0);
        }
    };

    f32x4 acc[4][4] = {};

    stage(0, 0);
    if (NKT > 1) stage(1, 1);

    for (int kt = 0; kt < NKT; ++kt) {
        if (kt + 1 < NKT) { asm volatile("s_waitcnt vmcnt(8)" ::: "memory"); }
        else             { asm volatile("s_waitcnt vmcnt(0)" ::: "memory"); }
        __builtin_amdgcn_s_barrier();          // all waves' stage(kt) landed
        __builtin_amdgcn_sched_barrier(0);

        const char* pa = smA[kt & 1] + (wr * 64) * 128;
        const char* pb = smB[kt & 1] + (wc * 64) * 128;
        #pragma unroll
        for (int kk = 0; kk < 2; ++kk) {
            const int kb = kk * 64 + kq * 16;
            bf16x8 av[4], bv[4];
            #pragma unroll
            for (int i = 0; i < 4; ++i) {
                av[i] = *(const bf16x8*)(pa + (i * 16 + r16) * 128 + (kb ^ swz));
                bv[i] = *(const bf16x8*)(pb + (i * 16 + r16) * 128 + (kb ^ swz));
            }
            #pragma unroll
            for (int mi = 0; mi < 4; ++mi)
                #pragma unroll
                for (int ni = 0; ni < 4; ++ni)
                    acc[mi][ni] = __builtin_amdgcn_mfma_f32_16x16x32_bf16(
                        av[mi], bv[ni], acc[mi][ni], 0, 0, 0);
        }

        __builtin_amdgcn_sched_barrier(0);
        __builtin_amdgcn_s_barrier();          // all waves done reading buf kt&1
        __builtin_amdgcn_sched_barrier(0);
        if (kt + 2 < NKT) stage(kt & 1, kt + 2);   // overwrite now-free buffer
    }

    // ---- epilogue: C/D layout col = lane&15, row = (lane>>4)*4 + reg ----
    if constexpr (QKVS) {
        const int q = o0 >> 9;
        u16* outp = (q == 0) ? oQ : (q == 1) ? oK : (q == 2) ? oV : oS;
        const int cb = (o0 & 511) + wc * 64;
        #pragma unroll
        for (int ni = 0; ni < 4; ++ni) {
            int col = cb + ni * 16 + r16;
            float b = bias[o0 + wc * 64 + ni * 16 + r16];
            #pragma unroll
            for (int mi = 0; mi < 4; ++mi)
                #pragma unroll
                for (int r = 0; r < 4; ++r) {
                    int gr = m0 + wr * 64 + mi * 16 + kq * 4 + r;
                    if (gr < n) outp[(size_t)gr * 512 + col] = f2bf(acc[mi][ni][r] + b);
                }
        }
    } else {
        const int cb = o0 + wc * 64;
        #pragma unroll
        for (int ni = 0; ni < 4; ++ni) {
            int col = cb + ni * 16 + r16;
            float b = bias[col];
            #pragma unroll
            for (int mi = 0; mi < 4; ++mi)
                #pragma unroll
                for (int r = 0; r < 4; ++r) {
                    int gr = m0 + wr * 64 + mi * 16 + kq * 4 + r;
                    if (gr < n) oF[(size_t)gr * Ototal + col] = acc[mi][ni][r] + b;
                }
        }
    }
}

// ---------------------------------------------------------------------------
// fp32 -> bf16 convert (count % 8 == 0); used for weights AND for x.
__global__ __launch_bounds__(256)
void cvt_w(const float* __restrict__ src, u16* __restrict__ dst, int n8)
{
    int i = blockIdx.x * 256 + threadIdx.x;
    if (i >= n8) return;
    const float4* s = (const float4*)src + (size_t)i * 2;
    float4 f0 = s[0], f1 = s[1];
    uint4 o;
    o.x = pack2(f0.x, f0.y); o.y = pack2(f0.z, f0.w);
    o.z = pack2(f1.x, f1.y); o.w = pack2(f1.z, f1.w);
    ((uint4*)dst)[i] = o;
}

// bias arena: [0..2047]=layer0 qkvs, [2048..4095]=layer1 qkvs, [4096..4479]=out
__global__ __launch_bounds__(256)
void pack_bias(const float* q0, const float* k0, const float* v0, const float* s0,
               const float* q1, const float* k1, const float* v1, const float* s1,
               const float* ob, float* __restrict__ dst)
{
    int i = blockIdx.x * 256 + threadIdx.x;
    if (i >= 4480) return;
    float v;
    if (i < 2048) {
        int j = i & 511, q = i >> 9;
        v = (q == 0 ? q0 : q == 1 ? k0 : q == 2 ? v0 : s0)[j];
    } else if (i < 4096) {
        int j = i - 2048; int q = j >> 9; j &= 511;
        v = (q == 0 ? q1 : q == 1 ? k1 : q == 2 ? v1 : s1)[j];
    } else {
        v = ob[i - 4096];
    }
    dst[i] = v;
}

// ---------------------------------------------------------------------------
// CSR build (order within bucket nondeterministic -> only permutes fp adds)
// ---------------------------------------------------------------------------
__global__ __launch_bounds__(256)
void zero_deg(int* __restrict__ deg)
{
    int i = blockIdx.x * 256 + threadIdx.x;
    if (i < NN) deg[i] = 0;
}

__global__ __launch_bounds__(256)
void hist_dst(const int* __restrict__ dst, int* __restrict__ deg)
{
    int e = blockIdx.x * 256 + threadIdx.x;
    if (e < NE) atomicAdd(&deg[dst[e]], 1);
}

__global__ __launch_bounds__(1024)
void scan_deg(const int* __restrict__ deg, int* __restrict__ rowptr,
              int* __restrict__ cursor)
{
    __shared__ int buf[1024];
    __shared__ int carry;
    int tid = threadIdx.x;
    if (tid == 0) carry = 0;
    __syncthreads();
    for (int base = 0; base < NN; base += 1024) {
        int i = base + tid;
        int v = (i < NN) ? deg[i] : 0;
        buf[tid] = v;
        __syncthreads();
        #pragma unroll
        for (int off = 1; off < 1024; off <<= 1) {
            int t = (tid >= off) ? buf[tid - off] : 0;
            __syncthreads();
            buf[tid] += t;
            __syncthreads();
        }
        int excl = carry + buf[tid] - v;
        if (i < NN) { rowptr[i] = excl; cursor[i] = excl; }
        __syncthreads();
        if (tid == 0) carry += buf[1023];
        __syncthreads();
    }
    if (tid == 0) rowptr[NN] = NE;
}

__global__ __launch_bounds__(256)
void scatter_edges(const int* __restrict__ src, const int* __restrict__ dst,
                   int* __restrict__ cursor, int* __restrict__ esrc_ord)
{
    int e = blockIdx.x * 256 + threadIdx.x;
    if (e >= NE) return;
    int pos = atomicAdd(&cursor[dst[e]], 1);
    esrc_ord[pos] = src[e];
}

// ---------------------------------------------------------------------------
// Fused per-node attention: one 64-lane wave per dst node; online softmax.
// Lane owns 8 contiguous channels; 16-lane group = one head.
// out = bf16(relu(agg + skip)), skip is bf16.
// ---------------------------------------------------------------------------
__global__ __launch_bounds__(256)
void node_attn(const u16* __restrict__ Qb, const u16* __restrict__ Kb,
               const u16* __restrict__ Vb, const int* __restrict__ rowptr,
               const int* __restrict__ esrc, const u16* __restrict__ skipb,
               u16* __restrict__ outb)
{
    int d = blockIdx.x * 4 + (threadIdx.x >> 6);
    if (d >= NN) return;
    int lane = threadIdx.x & 63;

    uint4 qv = *((const uint4*)(Qb + (size_t)d * HC) + lane);
    float q[8] = { bflo(qv.x), bfhi(qv.x), bflo(qv.y), bfhi(qv.y),
                   bflo(qv.z), bfhi(qv.z), bflo(qv.w), bfhi(qv.w) };

    int beg = rowptr[d], end = rowptr[d + 1];
    float m = -INFINITY, den = 0.f;
    float acc[8] = {};

    for (int i = beg; i < end; ++i) {
        int s = esrc[i];
        uint4 kv = *((const uint4*)(Kb + (size_t)s * HC) + lane);
        float sum = q[0] * bflo(kv.x) + q[1] * bfhi(kv.x)
                  + q[2] * bflo(kv.y) + q[3] * bfhi(kv.y)
                  + q[4] * bflo(kv.z) + q[5] * bfhi(kv.z)
                  + q[6] * bflo(kv.w) + q[7] * bfhi(kv.w);
        #pragma unroll
        for (int off = 1; off < 16; off <<= 1) sum += __shfl_xor(sum, off, 64);
        float alpha = sum * 0.08838834764831845f;

        float mnew  = fmaxf(m, alpha);
        float scale = __expf(m - mnew);      // first edge: exp(-inf)=0
        float p     = __expf(alpha - mnew);
        den = den * scale + p;

        uint4 vv = *((const uint4*)(Vb + (size_t)s * HC) + lane);
        acc[0] = acc[0] * scale + p * bflo(vv.x);
        acc[1] = acc[1] * scale + p * bfhi(vv.x);
        acc[2] = acc[2] * scale + p * bflo(vv.y);
        acc[3] = acc[3] * scale + p * bfhi(vv.y);
        acc[4] = acc[4] * scale + p * bflo(vv.z);
        acc[5] = acc[5] * scale + p * bfhi(vv.z);
        acc[6] = acc[6] * scale + p * bflo(vv.w);
        acc[7] = acc[7] * scale + p * bfhi(vv.w);
        m = mnew;
    }

    float inv = 1.f / (den + 1e-16f);
    size_t base = (size_t)d * HC + lane * 8;
    uint4 sv = *((const uint4*)(skipb + base));
    float sk[8] = { bflo(sv.x), bfhi(sv.x), bflo(sv.y), bfhi(sv.y),
                    bflo(sv.z), bfhi(sv.z), bflo(sv.w), bfhi(sv.w) };
    uint4 o;
    o.x = pack2(fmaxf(acc[0] * inv + sk[0], 0.f), fmaxf(acc[1] * inv + sk[1], 0.f));
    o.y = pack2(fmaxf(acc[2] * inv + sk[2], 0.f), fmaxf(acc[3] * inv + sk[3], 0.f));
    o.z = pack2(fmaxf(acc[4] * inv + sk[4], 0.f), fmaxf(acc[5] * inv + sk[5], 0.f));
    o.w = pack2(fmaxf(acc[6] * inv + sk[6], 0.f), fmaxf(acc[7] * inv + sk[7], 0.f));
    *(uint4*)(outb + base) = o;
}

// ---------------------------------------------------------------------------
extern "C" void kernel_launch(void* const* d_in, const int* in_sizes, int n_in,
                              void* d_out, int out_size, void* d_ws, size_t ws_size,
                              hipStream_t stream)
{
    const float* x   = (const float*)d_in[0];
    const int* ei    = (const int*)d_in[1];
    const int* esrc  = ei;
    const int* edst  = ei + NE;
    const float* q0w = (const float*)d_in[2];  const float* q0b = (const float*)d_in[3];
    const float* k0w = (const float*)d_in[4];  const float* k0b = (const float*)d_in[5];
    const float* v0w = (const float*)d_in[6];  const float* v0b = (const float*)d_in[7];
    const float* s0w = (const float*)d_in[8];  const float* s0b = (const float*)d_in[9];
    const float* q1w = (const float*)d_in[10]; const float* q1b = (const float*)d_in[11];
    const float* k1w = (const float*)d_in[12]; const float* k1b = (const float*)d_in[13];
    const float* v1w = (const float*)d_in[14]; const float* v1b = (const float*)d_in[15];
    const float* s1w = (const float*)d_in[16]; const float* s1b = (const float*)d_in[17];
    const float* ow  = (const float*)d_in[18]; const float* obs = (const float*)d_in[19];

    // ---- workspace (~247 MB) ----
    char* p = (char*)d_ws;
    auto take = [&](size_t bytes) { void* r = (void*)p; p += (bytes + 255) & ~(size_t)255; return r; };
    u16*   Qb     = (u16*)take((size_t)NN * HC * 2);       // 51.2 MB
    u16*   Vb     = (u16*)take((size_t)NN * HC * 2);       // 51.2 MB
    u16*   Hb     = (u16*)take((size_t)NN * HC * 2);       // 51.2 MB
    u16*   Sb     = (u16*)take((size_t)NN * HC * 2);       // 51.2 MB (bf16 skip)
    u16*   Xb     = (u16*)take((size_t)NN * DD * 2);       // 38.4 MB (bf16 x)
    u16*   Wc0    = (u16*)take((size_t)2048 * DD * 2);     // 1.57 MB
    u16*   Wc1    = (u16*)take((size_t)2048 * HC * 2);     // 2.10 MB
    u16*   WcO    = (u16*)take((size_t)DD * HC * 2);       // 0.39 MB
    float* barena = (float*)take(4480 * 4);                // 17.9 KB

    // ---- scratch carved from d_out (dead before final GEMM overwrites all) ----
    char* dob = (char*)d_out;
    u16* Kb       = (u16*)dob;                             // 51.2 MB
    int* deg      = (int*)(dob + 51200000);
    int* rowptr   = (int*)(dob + 51400192);                // NN+1
    int* cursor   = (int*)(dob + 51600384);
    int* esrc_ord = (int*)(dob + 51800576);                // 1.6 MB

    dim3 blk(256);
    int gN   = (NN + 255) / 256;
    int gE   = (NE + 255) / 256;
    int gnod = (NN + 3) / 4;
    const int NPAN = (NN + 127) / 128;   // 391 row panels
    int gq = NPAN * 16;                  // QKVS GEMM: 16 col-tiles
    int go = NPAN * 3;                   // out-proj: 3 col-tiles

    // ---- weight/bias/x prep ----
    pack_bias<<<(4480 + 255) / 256, blk, 0, stream>>>(q0b, k0b, v0b, s0b,
                                                      q1b, k1b, v1b, s1b, obs, barena);
    const int xn8 = NN * DD / 8;
    const int w0n8 = 512 * DD / 8, w1n8 = 512 * HC / 8, won8 = DD * HC / 8;
    cvt_w<<<(xn8 + 255) / 256, blk, 0, stream>>>(x, Xb, xn8);
    cvt_w<<<(w0n8 + 255) / 256, blk, 0, stream>>>(q0w, Wc0 + 0 * 512 * DD, w0n8);
    cvt_w<<<(w0n8 + 255) / 256, blk, 0, stream>>>(k0w, Wc0 + 1 * 512 * DD, w0n8);
    cvt_w<<<(w0n8 + 255) / 256, blk, 0, stream>>>(v0w, Wc0 + 2 * 512 * DD, w0n8);
    cvt_w<<<(w0n8 + 255) / 256, blk, 0, stream>>>(s0w, Wc0 + 3 * 512 * DD, w0n8);
    cvt_w<<<(w1n8 + 255) / 256, blk, 0, stream>>>(q1w, Wc1 + 0 * 512 * HC, w1n8);
    cvt_w<<<(w1n8 + 255) / 256, blk, 0, stream>>>(k1w, Wc1 + 1 * 512 * HC, w1n8);
    cvt_w<<<(w1n8 + 255) / 256, blk, 0, stream>>>(v1w, Wc1 + 2 * 512 * HC, w1n8);
    cvt_w<<<(w1n8 + 255) / 256, blk, 0, stream>>>(s1w, Wc1 + 3 * 512 * HC, w1n8);
    cvt_w<<<(won8 + 255) / 256, blk, 0, stream>>>(ow, WcO, won8);

    // ---- CSR build ----
    zero_deg      <<<gN, blk, 0, stream>>>(deg);
    hist_dst      <<<gE, blk, 0, stream>>>(edst, deg);
    scan_deg      <<<1, 1024, 0, stream>>>(deg, rowptr, cursor);
    scatter_edges <<<gE, blk, 0, stream>>>(esrc, edst, cursor, esrc_ord);

    // ---- layer 0 (A = Xb bf16, K=384) ----
    gemm2ph<DD, true><<<gq, blk, 0, stream>>>(Xb, Wc0, barena,
                                              Qb, Kb, Vb, Sb, nullptr, NN, 2048, 16);
    node_attn<<<gnod, blk, 0, stream>>>(Qb, Kb, Vb, rowptr, esrc_ord, Sb, Hb);

    // ---- layer 1 (A = Hb bf16, K=512) ----
    gemm2ph<HC, true><<<gq, blk, 0, stream>>>(Hb, Wc1, barena + 2048,
                                              Qb, Kb, Vb, Sb, nullptr, NN, 2048, 16);
    node_attn<<<gnod, blk, 0, stream>>>(Qb, Kb, Vb, rowptr, esrc_ord, Sb, Hb);

    // ---- output projection (fp32 out, overwrites ALL of d_out) ----
    gemm2ph<HC, false><<<go, blk, 0, stream>>>(Hb, WcO, barena + 4096,
                                               nullptr, nullptr, nullptr, nullptr,
                                               (float*)d_out, NN, 384, 3);
}

// Round 8
// 777.008 us; speedup vs baseline: 1.2686x; 1.2686x over previous
//
#include <hip/hip_runtime.h>
#include <hip/hip_bf16.h>

#define NN 50000   // nodes
#define NE 400000  // edges
#define DD 384     // input dim
#define HC 512     // heads * per-head dim (4 heads x 128)

typedef unsigned int u32;
typedef unsigned short u16;
typedef __attribute__((ext_vector_type(8))) short bf16x8;  // 8 bf16 (4 VGPRs)
typedef __attribute__((ext_vector_type(4))) float f32x4;

#define AS1 __attribute__((address_space(1)))
#define AS3 __attribute__((address_space(3)))

__device__ __forceinline__ float bflo(u32 u){ return __uint_as_float(u << 16); }
__device__ __forceinline__ float bfhi(u32 u){ return __uint_as_float(u & 0xFFFF0000u); }
__device__ __forceinline__ u16 f2bf(float f){
    u32 u = __float_as_uint(f);
    return (u16)((u + 0x7FFFu + ((u >> 16) & 1u)) >> 16);   // RNE
}
__device__ __forceinline__ u32 pack2(float a, float b){
    return (u32)f2bf(a) | ((u32)f2bf(b) << 16);
}

// ---------------------------------------------------------------------------
// Persistent weight-stationary QKVS GEMM.
// Grid = 256 blocks (1/CU, 160 KB LDS), 512 threads = 8 waves.
// Block identity: xcd = bid&7, col-tile ct = (bid>>3)&15, row-half rh = bid>>7.
// W[ct*128 .. +128)[K] staged to LDS ONCE (128 KB @K=512); A panels stream
// through a 2-deep 2x16 KB dbuf with counted vmcnt(2) — ~200-step pipeline
// (24-25 panels x K/64 chunks) so fill/drain is amortized away.
// All 16 col-tile blocks of an XCD walk the same panel list (p%8==xcd) ->
// A HBM-fetched ~once chip-wide, L2-shared within the XCD.
// Wave (wq=w>>1, wc=w&1) owns 32 rows x 64 cols; 16x16x32 MFMA; XOR-swizzled
// 16B chunks (chunk ^= row&7) on stage-source and LDS reads (proven 0-conflict).
// ---------------------------------------------------------------------------
template<int K>
__global__ __launch_bounds__(512)
void gemm_ws(const u16* __restrict__ Ab, const u16* __restrict__ Wb,
             const float* __restrict__ bias,
             u16* __restrict__ oQ, u16* __restrict__ oK,
             u16* __restrict__ oV, u16* __restrict__ oS)
{
    constexpr int NKT  = K / 64;        // A k-chunks per panel
    constexpr int WCH  = K / 8;         // 16B chunks per W row
    constexpr int NPAN = (NN + 127) / 128;
    __shared__ char smW[128 * K * 2];   // 128 KB @K=512, 96 KB @K=384
    __shared__ char smA[2][16384];      // [buf][128 rows][64 k x 2B]

    const int b   = blockIdx.x;
    const int xcd = b & 7;
    const int idx = b >> 3;
    const int ct  = idx & 15;           // col-tile (128 cols of 2048)
    const int rh  = idx >> 4;           // row-half (0/1)

    const int tid  = threadIdx.x;
    const int lane = tid & 63;
    const int w    = tid >> 6;
    const int wq   = w >> 1;            // row quarter 0..3 (32 rows)
    const int wc   = w & 1;             // col half 0..1 (64 cols)
    const int r16  = lane & 15;
    const int kq   = lane >> 4;

    // ---- stage W once ----
    const u16* Wrow0 = Wb + (size_t)ct * 128 * K;
    #pragma unroll
    for (int p = 0; p < (128 * WCH) / 512; ++p) {
        int ci = p * 512 + tid;
        int row = ci / WCH, pc = ci % WCH;
        int lc = (pc & ~7) | ((pc ^ row) & 7);
        __builtin_amdgcn_global_load_lds((const AS1 u32*)(Wrow0 + (size_t)row * K + lc * 8),
                                         (AS3 u32*)(smW + (size_t)ci * 16), 16, 0, 0);
    }

    // ---- panel list: p = (2j+rh)*8 + xcd ----
    auto panel = [&](int j) { return (2 * j + rh) * 8 + xcd; };
    int np = 0;
    while (panel(np) < NPAN) ++np;      // 24 or 25
    const int total = np * NKT;

    // A stage: 1024 chunks over 512 threads -> 2 gload_lds/thread
    auto stageA = [&](int t) {
        int j = t / NKT, kc = t - (t / NKT) * NKT;
        int m0 = panel(j) * 128;
        #pragma unroll
        for (int p = 0; p < 2; ++p) {
            int ci = p * 512 + tid;
            int row = ci >> 3, pc = ci & 7;
            int lc = pc ^ (row & 7);
            int gr = m0 + row; if (gr >= NN) gr = NN - 1;
            __builtin_amdgcn_global_load_lds((const AS1 u32*)(Ab + (size_t)gr * K + kc * 64 + lc * 8),
                                             (AS3 u32*)(smA[t & 1] + ci * 16), 16, 0, 0);
        }
    };

    stageA(0);
    stageA(1);

    f32x4 acc[2][4] = {};

    const int qsel = ct >> 2;
    u16* outp = (qsel == 0) ? oQ : (qsel == 1) ? oK : (qsel == 2) ? oV : oS;
    const int cb = (ct & 3) * 128 + wc * 64;
    float bv4[4];
    #pragma unroll
    for (int ni = 0; ni < 4; ++ni) bv4[ni] = bias[ct * 128 + wc * 64 + ni * 16 + r16];

    for (int t = 0; t < total; ++t) {
        if (t + 1 < total) { asm volatile("s_waitcnt vmcnt(2)" ::: "memory"); }
        else               { asm volatile("s_waitcnt vmcnt(0)" ::: "memory"); }
        __builtin_amdgcn_s_barrier();          // stage(t) landed for all waves
        __builtin_amdgcn_sched_barrier(0);

        const int jj = t / NKT;
        const int kt = t - jj * NKT;
        const char* bufA = smA[t & 1];
        #pragma unroll
        for (int kk = 0; kk < 2; ++kk) {
            bf16x8 av[2], bv[4];
            #pragma unroll
            for (int i = 0; i < 2; ++i) {
                int rowA = wq * 32 + i * 16 + r16;
                int c = kk * 4 + kq;
                av[i] = *(const bf16x8*)(bufA + rowA * 128 + ((c ^ (rowA & 7)) << 4));
            }
            #pragma unroll
            for (int i = 0; i < 4; ++i) {
                int rowW = wc * 64 + i * 16 + r16;
                int c = kt * 8 + kk * 4 + kq;
                int pcw = (c & ~7) | ((c ^ rowW) & 7);
                bv[i] = *(const bf16x8*)(smW + (size_t)rowW * (K * 2) + (pcw << 4));
            }
            #pragma unroll
            for (int mi = 0; mi < 2; ++mi)
                #pragma unroll
                for (int ni = 0; ni < 4; ++ni)
                    acc[mi][ni] = __builtin_amdgcn_mfma_f32_16x16x32_bf16(
                        av[mi], bv[ni], acc[mi][ni], 0, 0, 0);
        }

        __builtin_amdgcn_sched_barrier(0);
        __builtin_amdgcn_s_barrier();          // all waves done reading buf t&1
        __builtin_amdgcn_sched_barrier(0);

        if (kt == NKT - 1) {                   // panel finished: epilogue
            int m0 = panel(jj) * 128;
            #pragma unroll
            for (int ni = 0; ni < 4; ++ni) {
                int col = cb + ni * 16 + r16;
                float bb = bv4[ni];
                #pragma unroll
                for (int mi = 0; mi < 2; ++mi)
                    #pragma unroll
                    for (int r = 0; r < 4; ++r) {
                        int gr = m0 + wq * 32 + mi * 16 + kq * 4 + r;
                        if (gr < NN) outp[(size_t)gr * 512 + col] = f2bf(acc[mi][ni][r] + bb);
                        acc[mi][ni][r] = 0.f;
                    }
            }
        }
        if (t + 2 < total) stageA(t + 2);      // overwrite now-free buffer
    }
}

// ---------------------------------------------------------------------------
// 2-deep pipelined MFMA GEMM (round-7 structure) — kept for the out-proj.
// ---------------------------------------------------------------------------
template<int K>
__global__ __launch_bounds__(256)
void gemm2ph(const u16* __restrict__ Ab, const u16* __restrict__ Wb,
             const float* __restrict__ bias, float* __restrict__ oF,
             int n, int Ototal, int NT)
{
    constexpr int NKT = K / 64;
    __shared__ char smA[2][16384];
    __shared__ char smB[2][16384];

    const int nb  = gridDim.x;
    const int bd  = blockIdx.x;
    const int q8  = nb >> 3, r8 = nb & 7;
    const int xcd = bd & 7, gg = bd >> 3;
    const int tt  = (xcd < r8 ? xcd * (q8 + 1) : r8 * (q8 + 1) + (xcd - r8) * q8) + gg;
    const int m0  = (tt / NT) * 128;
    const int o0  = (tt % NT) * 128;

    const int tid  = threadIdx.x;
    const int lane = tid & 63;
    const int w    = tid >> 6;
    const int wr   = w >> 1, wc = w & 1;
    const int r16  = lane & 15;
    const int kq   = lane >> 4;
    const int swz  = (r16 & 7) << 4;

    auto stage = [&](int bf, int kt) {
        #pragma unroll
        for (int p = 0; p < 4; ++p) {
            int ci = p * 256 + tid, row = ci >> 3, pc = ci & 7;
            int lc = pc ^ (row & 7);
            const u16* g = Wb + (size_t)(o0 + row) * K + kt * 64 + lc * 8;
            __builtin_amdgcn_global_load_lds((const AS1 u32*)g,
                                             (AS3 u32*)(smB[bf] + ci * 16), 16, 0, 0);
        }
        #pragma unroll
        for (int p = 0; p < 4; ++p) {
            int ci = p * 256 + tid, row = ci >> 3, pc = ci & 7;
            int lc = pc ^ (row & 7);
            int gr = m0 + row; if (gr >= n) gr = n - 1;
            const u16* g = Ab + (size_t)gr * K + kt * 64 + lc * 8;
            __builtin_amdgcn_global_load_lds((const AS1 u32*)g,
                                             (AS3 u32*)(smA[bf] + ci * 16), 16, 0, 0);
        }
    };

    f32x4 acc[4][4] = {};

    stage(0, 0);
    stage(1, 1);

    for (int kt = 0; kt < NKT; ++kt) {
        if (kt + 1 < NKT) { asm volatile("s_waitcnt vmcnt(8)" ::: "memory"); }
        else             { asm volatile("s_waitcnt vmcnt(0)" ::: "memory"); }
        __builtin_amdgcn_s_barrier();
        __builtin_amdgcn_sched_barrier(0);

        const char* pa = smA[kt & 1] + (wr * 64) * 128;
        const char* pb = smB[kt & 1] + (wc * 64) * 128;
        #pragma unroll
        for (int kk = 0; kk < 2; ++kk) {
            const int kb = kk * 64 + kq * 16;
            bf16x8 av[4], bv[4];
            #pragma unroll
            for (int i = 0; i < 4; ++i) {
                av[i] = *(const bf16x8*)(pa + (i * 16 + r16) * 128 + (kb ^ swz));
                bv[i] = *(const bf16x8*)(pb + (i * 16 + r16) * 128 + (kb ^ swz));
            }
            #pragma unroll
            for (int mi = 0; mi < 4; ++mi)
                #pragma unroll
                for (int ni = 0; ni < 4; ++ni)
                    acc[mi][ni] = __builtin_amdgcn_mfma_f32_16x16x32_bf16(
                        av[mi], bv[ni], acc[mi][ni], 0, 0, 0);
        }

        __builtin_amdgcn_sched_barrier(0);
        __builtin_amdgcn_s_barrier();
        __builtin_amdgcn_sched_barrier(0);
        if (kt + 2 < NKT) stage(kt & 1, kt + 2);
    }

    const int cb = o0 + wc * 64;
    #pragma unroll
    for (int ni = 0; ni < 4; ++ni) {
        int col = cb + ni * 16 + r16;
        float bb = bias[col];
        #pragma unroll
        for (int mi = 0; mi < 4; ++mi)
            #pragma unroll
            for (int r = 0; r < 4; ++r) {
                int gr = m0 + wr * 64 + mi * 16 + kq * 4 + r;
                if (gr < n) oF[(size_t)gr * Ototal + col] = acc[mi][ni][r] + bb;
            }
    }
}

// ---------------------------------------------------------------------------
// fp32 -> bf16 convert (count % 8 == 0); used for weights AND for x.
__global__ __launch_bounds__(256)
void cvt_w(const float* __restrict__ src, u16* __restrict__ dst, int n8)
{
    int i = blockIdx.x * 256 + threadIdx.x;
    if (i >= n8) return;
    const float4* s = (const float4*)src + (size_t)i * 2;
    float4 f0 = s[0], f1 = s[1];
    uint4 o;
    o.x = pack2(f0.x, f0.y); o.y = pack2(f0.z, f0.w);
    o.z = pack2(f1.x, f1.y); o.w = pack2(f1.z, f1.w);
    ((uint4*)dst)[i] = o;
}

// bias arena: [0..2047]=layer0 qkvs, [2048..4095]=layer1 qkvs, [4096..4479]=out
__global__ __launch_bounds__(256)
void pack_bias(const float* q0, const float* k0, const float* v0, const float* s0,
               const float* q1, const float* k1, const float* v1, const float* s1,
               const float* ob, float* __restrict__ dst)
{
    int i = blockIdx.x * 256 + threadIdx.x;
    if (i >= 4480) return;
    float v;
    if (i < 2048) {
        int j = i & 511, q = i >> 9;
        v = (q == 0 ? q0 : q == 1 ? k0 : q == 2 ? v0 : s0)[j];
    } else if (i < 4096) {
        int j = i - 2048; int q = j >> 9; j &= 511;
        v = (q == 0 ? q1 : q == 1 ? k1 : q == 2 ? v1 : s1)[j];
    } else {
        v = ob[i - 4096];
    }
    dst[i] = v;
}

// ---------------------------------------------------------------------------
// CSR build (order within bucket nondeterministic -> only permutes fp adds)
// ---------------------------------------------------------------------------
__global__ __launch_bounds__(256)
void zero_deg(int* __restrict__ deg)
{
    int i = blockIdx.x * 256 + threadIdx.x;
    if (i < NN) deg[i] = 0;
}

__global__ __launch_bounds__(256)
void hist_dst(const int* __restrict__ dst, int* __restrict__ deg)
{
    int e = blockIdx.x * 256 + threadIdx.x;
    if (e < NE) atomicAdd(&deg[dst[e]], 1);
}

__global__ __launch_bounds__(1024)
void scan_deg(const int* __restrict__ deg, int* __restrict__ rowptr,
              int* __restrict__ cursor)
{
    __shared__ int buf[1024];
    __shared__ int carry;
    int tid = threadIdx.x;
    if (tid == 0) carry = 0;
    __syncthreads();
    for (int base = 0; base < NN; base += 1024) {
        int i = base + tid;
        int v = (i < NN) ? deg[i] : 0;
        buf[tid] = v;
        __syncthreads();
        #pragma unroll
        for (int off = 1; off < 1024; off <<= 1) {
            int t = (tid >= off) ? buf[tid - off] : 0;
            __syncthreads();
            buf[tid] += t;
            __syncthreads();
        }
        int excl = carry + buf[tid] - v;
        if (i < NN) { rowptr[i] = excl; cursor[i] = excl; }
        __syncthreads();
        if (tid == 0) carry += buf[1023];
        __syncthreads();
    }
    if (tid == 0) rowptr[NN] = NE;
}

__global__ __launch_bounds__(256)
void scatter_edges(const int* __restrict__ src, const int* __restrict__ dst,
                   int* __restrict__ cursor, int* __restrict__ esrc_ord)
{
    int e = blockIdx.x * 256 + threadIdx.x;
    if (e >= NE) return;
    int pos = atomicAdd(&cursor[dst[e]], 1);
    esrc_ord[pos] = src[e];
}

// ---------------------------------------------------------------------------
// Fused per-node attention: one 64-lane wave per dst node; online softmax.
// Lane owns 8 contiguous channels; 16-lane group = one head.
// out = bf16(relu(agg + skip)), skip is bf16.
// ---------------------------------------------------------------------------
__global__ __launch_bounds__(256)
void node_attn(const u16* __restrict__ Qb, const u16* __restrict__ Kb,
               const u16* __restrict__ Vb, const int* __restrict__ rowptr,
               const int* __restrict__ esrc, const u16* __restrict__ skipb,
               u16* __restrict__ outb)
{
    int d = blockIdx.x * 4 + (threadIdx.x >> 6);
    if (d >= NN) return;
    int lane = threadIdx.x & 63;

    uint4 qv = *((const uint4*)(Qb + (size_t)d * HC) + lane);
    float q[8] = { bflo(qv.x), bfhi(qv.x), bflo(qv.y), bfhi(qv.y),
                   bflo(qv.z), bfhi(qv.z), bflo(qv.w), bfhi(qv.w) };

    int beg = rowptr[d], end = rowptr[d + 1];
    float m = -INFINITY, den = 0.f;
    float acc[8] = {};

    for (int i = beg; i < end; ++i) {
        int s = esrc[i];
        uint4 kv = *((const uint4*)(Kb + (size_t)s * HC) + lane);
        float sum = q[0] * bflo(kv.x) + q[1] * bfhi(kv.x)
                  + q[2] * bflo(kv.y) + q[3] * bfhi(kv.y)
                  + q[4] * bflo(kv.z) + q[5] * bfhi(kv.z)
                  + q[6] * bflo(kv.w) + q[7] * bfhi(kv.w);
        #pragma unroll
        for (int off = 1; off < 16; off <<= 1) sum += __shfl_xor(sum, off, 64);
        float alpha = sum * 0.08838834764831845f;

        float mnew  = fmaxf(m, alpha);
        float scale = __expf(m - mnew);      // first edge: exp(-inf)=0
        float p     = __expf(alpha - mnew);
        den = den * scale + p;

        uint4 vv = *((const uint4*)(Vb + (size_t)s * HC) + lane);
        acc[0] = acc[0] * scale + p * bflo(vv.x);
        acc[1] = acc[1] * scale + p * bfhi(vv.x);
        acc[2] = acc[2] * scale + p * bflo(vv.y);
        acc[3] = acc[3] * scale + p * bfhi(vv.y);
        acc[4] = acc[4] * scale + p * bflo(vv.z);
        acc[5] = acc[5] * scale + p * bfhi(vv.z);
        acc[6] = acc[6] * scale + p * bflo(vv.w);
        acc[7] = acc[7] * scale + p * bfhi(vv.w);
        m = mnew;
    }

    float inv = 1.f / (den + 1e-16f);
    size_t base = (size_t)d * HC + lane * 8;
    uint4 sv = *((const uint4*)(skipb + base));
    float sk[8] = { bflo(sv.x), bfhi(sv.x), bflo(sv.y), bfhi(sv.y),
                    bflo(sv.z), bfhi(sv.z), bflo(sv.w), bfhi(sv.w) };
    uint4 o;
    o.x = pack2(fmaxf(acc[0] * inv + sk[0], 0.f), fmaxf(acc[1] * inv + sk[1], 0.f));
    o.y = pack2(fmaxf(acc[2] * inv + sk[2], 0.f), fmaxf(acc[3] * inv + sk[3], 0.f));
    o.z = pack2(fmaxf(acc[4] * inv + sk[4], 0.f), fmaxf(acc[5] * inv + sk[5], 0.f));
    o.w = pack2(fmaxf(acc[6] * inv + sk[6], 0.f), fmaxf(acc[7] * inv + sk[7], 0.f));
    *(uint4*)(outb + base) = o;
}

// ---------------------------------------------------------------------------
extern "C" void kernel_launch(void* const* d_in, const int* in_sizes, int n_in,
                              void* d_out, int out_size, void* d_ws, size_t ws_size,
                              hipStream_t stream)
{
    const float* x   = (const float*)d_in[0];
    const int* ei    = (const int*)d_in[1];
    const int* esrc  = ei;
    const int* edst  = ei + NE;
    const float* q0w = (const float*)d_in[2];  const float* q0b = (const float*)d_in[3];
    const float* k0w = (const float*)d_in[4];  const float* k0b = (const float*)d_in[5];
    const float* v0w = (const float*)d_in[6];  const float* v0b = (const float*)d_in[7];
    const float* s0w = (const float*)d_in[8];  const float* s0b = (const float*)d_in[9];
    const float* q1w = (const float*)d_in[10]; const float* q1b = (const float*)d_in[11];
    const float* k1w = (const float*)d_in[12]; const float* k1b = (const float*)d_in[13];
    const float* v1w = (const float*)d_in[14]; const float* v1b = (const float*)d_in[15];
    const float* s1w = (const float*)d_in[16]; const float* s1b = (const float*)d_in[17];
    const float* ow  = (const float*)d_in[18]; const float* obs = (const float*)d_in[19];

    // ---- workspace (~247 MB) ----
    char* p = (char*)d_ws;
    auto take = [&](size_t bytes) { void* r = (void*)p; p += (bytes + 255) & ~(size_t)255; return r; };
    u16*   Qb     = (u16*)take((size_t)NN * HC * 2);       // 51.2 MB
    u16*   Vb     = (u16*)take((size_t)NN * HC * 2);       // 51.2 MB
    u16*   Hb     = (u16*)take((size_t)NN * HC * 2);       // 51.2 MB
    u16*   Sb     = (u16*)take((size_t)NN * HC * 2);       // 51.2 MB (bf16 skip)
    u16*   Xb     = (u16*)take((size_t)NN * DD * 2);       // 38.4 MB (bf16 x)
    u16*   Wc0    = (u16*)take((size_t)2048 * DD * 2);     // 1.57 MB
    u16*   Wc1    = (u16*)take((size_t)2048 * HC * 2);     // 2.10 MB
    u16*   WcO    = (u16*)take((size_t)DD * HC * 2);       // 0.39 MB
    float* barena = (float*)take(4480 * 4);                // 17.9 KB

    // ---- scratch carved from d_out (dead before final GEMM overwrites all) ----
    char* dob = (char*)d_out;
    u16* Kb       = (u16*)dob;                             // 51.2 MB
    int* deg      = (int*)(dob + 51200000);
    int* rowptr   = (int*)(dob + 51400192);                // NN+1
    int* cursor   = (int*)(dob + 51600384);
    int* esrc_ord = (int*)(dob + 51800576);                // 1.6 MB

    dim3 blk(256);
    int gN   = (NN + 255) / 256;
    int gE   = (NE + 255) / 256;
    int gnod = (NN + 3) / 4;
    const int NPAN = (NN + 127) / 128;   // 391 row panels
    int go = NPAN * 3;                   // out-proj: 3 col-tiles

    // ---- weight/bias/x prep ----
    pack_bias<<<(4480 + 255) / 256, blk, 0, stream>>>(q0b, k0b, v0b, s0b,
                                                      q1b, k1b, v1b, s1b, obs, barena);
    const int xn8 = NN * DD / 8;
    const int w0n8 = 512 * DD / 8, w1n8 = 512 * HC / 8, won8 = DD * HC / 8;
    cvt_w<<<(xn8 + 255) / 256, blk, 0, stream>>>(x, Xb, xn8);
    cvt_w<<<(w0n8 + 255) / 256, blk, 0, stream>>>(q0w, Wc0 + 0 * 512 * DD, w0n8);
    cvt_w<<<(w0n8 + 255) / 256, blk, 0, stream>>>(k0w, Wc0 + 1 * 512 * DD, w0n8);
    cvt_w<<<(w0n8 + 255) / 256, blk, 0, stream>>>(v0w, Wc0 + 2 * 512 * DD, w0n8);
    cvt_w<<<(w0n8 + 255) / 256, blk, 0, stream>>>(s0w, Wc0 + 3 * 512 * DD, w0n8);
    cvt_w<<<(w1n8 + 255) / 256, blk, 0, stream>>>(q1w, Wc1 + 0 * 512 * HC, w1n8);
    cvt_w<<<(w1n8 + 255) / 256, blk, 0, stream>>>(k1w, Wc1 + 1 * 512 * HC, w1n8);
    cvt_w<<<(w1n8 + 255) / 256, blk, 0, stream>>>(v1w, Wc1 + 2 * 512 * HC, w1n8);
    cvt_w<<<(w1n8 + 255) / 256, blk, 0, stream>>>(s1w, Wc1 + 3 * 512 * HC, w1n8);
    cvt_w<<<(won8 + 255) / 256, blk, 0, stream>>>(ow, WcO, won8);

    // ---- CSR build ----
    zero_deg      <<<gN, blk, 0, stream>>>(deg);
    hist_dst      <<<gE, blk, 0, stream>>>(edst, deg);
    scan_deg      <<<1, 1024, 0, stream>>>(deg, rowptr, cursor);
    scatter_edges <<<gE, blk, 0, stream>>>(esrc, edst, cursor, esrc_ord);

    // ---- layer 0 (A = Xb bf16, K=384) ----
    gemm_ws<DD><<<256, 512, 0, stream>>>(Xb, Wc0, barena, Qb, Kb, Vb, Sb);
    node_attn<<<gnod, blk, 0, stream>>>(Qb, Kb, Vb, rowptr, esrc_ord, Sb, Hb);

    // ---- layer 1 (A = Hb bf16, K=512) ----
    gemm_ws<HC><<<256, 512, 0, stream>>>(Hb, Wc1, barena + 2048, Qb, Kb, Vb, Sb);
    node_attn<<<gnod, blk, 0, stream>>>(Qb, Kb, Vb, rowptr, esrc_ord, Sb, Hb);

    // ---- output projection (fp32 out, overwrites ALL of d_out) ----
    gemm2ph<HC><<<go, blk, 0, stream>>>(Hb, WcO, barena + 4096,
                                        (float*)d_out, NN, 384, 3);
}

// Round 9
// 736.298 us; speedup vs baseline: 1.3388x; 1.0553x over previous
//
#include <hip/hip_runtime.h>
#include <hip/hip_bf16.h>

#define NN 50000   // nodes
#define NE 400000  // edges
#define DD 384     // input dim
#define HC 512     // heads * per-head dim (4 heads x 128)

typedef unsigned int u32;
typedef unsigned short u16;
typedef __attribute__((ext_vector_type(8))) short bf16x8;  // 8 bf16 (4 VGPRs)
typedef __attribute__((ext_vector_type(4))) float f32x4;

#define AS1 __attribute__((address_space(1)))
#define AS3 __attribute__((address_space(3)))

__device__ __forceinline__ float bflo(u32 u){ return __uint_as_float(u << 16); }
__device__ __forceinline__ float bfhi(u32 u){ return __uint_as_float(u & 0xFFFF0000u); }
__device__ __forceinline__ u16 f2bf(float f){
    u32 u = __float_as_uint(f);
    return (u16)((u + 0x7FFFu + ((u >> 16) & 1u)) >> 16);   // RNE
}
__device__ __forceinline__ u32 pack2(float a, float b){
    return (u32)f2bf(a) | ((u32)f2bf(b) << 16);
}

// ---------------------------------------------------------------------------
// Persistent weight-stationary QKVS GEMM, v2.
// Grid = 256 blocks (1/CU), 512 threads = 8 waves, LDS = 160 KB (K=512).
// W subtiled [NKC][128 rows][4 slots x 16B] — 64-B rows, slot = kq ^ (row&3):
//   the round-7-proven conflict-free geometry. Staged ONCE via reg->ds_write.
// A streams as PANEL PAIRS: per step (2 panels x 32-k chunk) each bv LDS read
//   feeds 2 panels' MFMAs -> 8 ds_read_b128 + 16 MFMA/wave/step (~balanced).
// A dbuf [2][2 panels][128][64B] = 32 KB, counted vmcnt(2), ~200-step pipeline.
// Block: xcd=bid&7 (panels p%8==xcd -> A L2-shared), ct=col-tile, rh=row-half.
// ---------------------------------------------------------------------------
template<int K>
__global__ __launch_bounds__(512)
void gemm_ws(const u16* __restrict__ Ab, const u16* __restrict__ Wb,
             const float* __restrict__ bias,
             u16* __restrict__ oQ, u16* __restrict__ oK,
             u16* __restrict__ oV, u16* __restrict__ oS)
{
    constexpr int NKC  = K / 32;        // 32-k chunks (12 or 16)
    constexpr int NPAN = (NN + 127) / 128;
    __shared__ char smW[NKC * 8192];    // 96/128 KB, k-chunk-major subtiles
    __shared__ char smA[2][16384];      // [buf][2 panels][128 rows][64 B]

    const int b   = blockIdx.x;
    const int xcd = b & 7;
    const int idx = b >> 3;
    const int ct  = idx & 15;           // col-tile (128 of 2048)
    const int rh  = idx >> 4;           // row-half (0/1)

    const int tid  = threadIdx.x;
    const int lane = tid & 63;
    const int w    = tid >> 6;
    const int wq   = w >> 1;            // row quarter (32 rows)
    const int wc   = w & 1;             // col half (64 cols)
    const int r16  = lane & 15;
    const int kq   = lane >> 4;

    // ---- stage W once: global -> reg -> subtiled ds_write ----
    {
        const u16* Wrow0 = Wb + (size_t)ct * 128 * K;
        const int row = tid >> 2, pc = tid & 3;
        const int lc  = pc ^ (row & 3);
        #pragma unroll
        for (int kt = 0; kt < NKC; ++kt) {
            uint4 v = *(const uint4*)(Wrow0 + (size_t)row * K + kt * 32 + lc * 8);
            *(uint4*)(smW + kt * 8192 + tid * 16) = v;   // = kt*8192 + row*64 + pc*16
        }
    }
    asm volatile("s_waitcnt lgkmcnt(0)" ::: "memory");
    __builtin_amdgcn_sched_barrier(0);

    // ---- panel bookkeeping: panels p = (2j+rh)*8 + xcd, j = 0.. ----
    int np = 0;
    while ((2 * np + rh) * 8 + xcd < NPAN) ++np;         // 24 or 25
    const int npair = (np + 1) / 2;
    const int total = npair * NKC;

    // A pair-chunk stage: 2 gload_lds/thread -> vmcnt unit = 2
    auto stageA = [&](int t2) {
        int jp2 = t2 / NKC, kc2 = t2 - jp2 * NKC;
        int p0 = (4 * jp2 + rh) * 8 + xcd;
        int p1 = (2 * jp2 + 1 < np) ? p0 + 16 : p0;
        const int row = tid >> 2, pc = tid & 3;
        const int lc  = pc ^ (row & 3);
        #pragma unroll
        for (int p = 0; p < 2; ++p) {
            int pan = p ? p1 : p0;
            int gr = pan * 128 + row; if (gr >= NN) gr = NN - 1;
            __builtin_amdgcn_global_load_lds(
                (const AS1 u32*)(Ab + (size_t)gr * K + kc2 * 32 + lc * 8),
                (AS3 u32*)(smA[t2 & 1] + (p * 512 + tid) * 16), 16, 0, 0);
        }
    };

    stageA(0);
    if (total > 1) stageA(1);

    f32x4 acc[2][2][4] = {};            // [panel][row-frag][col-frag]

    const int qsel = ct >> 2;
    u16* outp = (qsel == 0) ? oQ : (qsel == 1) ? oK : (qsel == 2) ? oV : oS;
    const int cb = (ct & 3) * 128 + wc * 64;
    float bv4[4];
    #pragma unroll
    for (int ni = 0; ni < 4; ++ni) bv4[ni] = bias[ct * 128 + wc * 64 + ni * 16 + r16];

    for (int t = 0; t < total; ++t) {
        if (t + 1 < total) { asm volatile("s_waitcnt vmcnt(2)" ::: "memory"); }
        else               { asm volatile("s_waitcnt vmcnt(0)" ::: "memory"); }
        __builtin_amdgcn_s_barrier();          // stage(t) landed for all waves
        __builtin_amdgcn_sched_barrier(0);

        const int jp = t / NKC;
        const int kc = t - jp * NKC;
        const char* bufA = smA[t & 1];

        bf16x8 bv[4];
        #pragma unroll
        for (int ni = 0; ni < 4; ++ni) {
            int rowW = wc * 64 + ni * 16 + r16;
            bv[ni] = *(const bf16x8*)(smW + kc * 8192 + rowW * 64
                                      + ((kq ^ (rowW & 3)) << 4));
        }
        #pragma unroll
        for (int q = 0; q < 2; ++q) {
            #pragma unroll
            for (int mi = 0; mi < 2; ++mi) {
                int rowA = wq * 32 + mi * 16 + r16;
                bf16x8 av = *(const bf16x8*)(bufA + q * 8192 + rowA * 64
                                             + ((kq ^ (rowA & 3)) << 4));
                #pragma unroll
                for (int ni = 0; ni < 4; ++ni)
                    acc[q][mi][ni] = __builtin_amdgcn_mfma_f32_16x16x32_bf16(
                        av, bv[ni], acc[q][mi][ni], 0, 0, 0);
            }
        }

        __builtin_amdgcn_sched_barrier(0);
        __builtin_amdgcn_s_barrier();          // all waves done with buf t&1
        __builtin_amdgcn_sched_barrier(0);

        if (kc == NKC - 1) {                   // pair finished: epilogue
            int p0 = (4 * jp + rh) * 8 + xcd;
            int p1 = (2 * jp + 1 < np) ? p0 + 16 : p0;
            #pragma unroll
            for (int q = 0; q < 2; ++q) {
                int m0 = (q ? p1 : p0) * 128;
                #pragma unroll
                for (int ni = 0; ni < 4; ++ni) {
                    int col = cb + ni * 16 + r16;
                    float bb = bv4[ni];
                    #pragma unroll
                    for (int mi = 0; mi < 2; ++mi)
                        #pragma unroll
                        for (int r = 0; r < 4; ++r) {
                            int gr = m0 + wq * 32 + mi * 16 + kq * 4 + r;
                            if (gr < NN)
                                outp[(size_t)gr * 512 + col] = f2bf(acc[q][mi][ni][r] + bb);
                            acc[q][mi][ni][r] = 0.f;
                        }
                }
            }
        }
        if (t + 2 < total) stageA(t + 2);      // overwrite now-free buffer
    }
}

// ---------------------------------------------------------------------------
// 2-deep pipelined MFMA GEMM (round-7 structure) — output projection.
// ---------------------------------------------------------------------------
template<int K>
__global__ __launch_bounds__(256)
void gemm2ph(const u16* __restrict__ Ab, const u16* __restrict__ Wb,
             const float* __restrict__ bias, float* __restrict__ oF,
             int n, int Ototal, int NT)
{
    constexpr int NKT = K / 64;
    __shared__ char smA[2][16384];
    __shared__ char smB[2][16384];

    const int nb  = gridDim.x;
    const int bd  = blockIdx.x;
    const int q8  = nb >> 3, r8 = nb & 7;
    const int xcd = bd & 7, gg = bd >> 3;
    const int tt  = (xcd < r8 ? xcd * (q8 + 1) : r8 * (q8 + 1) + (xcd - r8) * q8) + gg;
    const int m0  = (tt / NT) * 128;
    const int o0  = (tt % NT) * 128;

    const int tid  = threadIdx.x;
    const int lane = tid & 63;
    const int w    = tid >> 6;
    const int wr   = w >> 1, wc = w & 1;
    const int r16  = lane & 15;
    const int kq   = lane >> 4;
    const int swz  = (r16 & 7) << 4;

    auto stage = [&](int bf, int kt) {
        #pragma unroll
        for (int p = 0; p < 4; ++p) {
            int ci = p * 256 + tid, row = ci >> 3, pc = ci & 7;
            int lc = pc ^ (row & 7);
            const u16* g = Wb + (size_t)(o0 + row) * K + kt * 64 + lc * 8;
            __builtin_amdgcn_global_load_lds((const AS1 u32*)g,
                                             (AS3 u32*)(smB[bf] + ci * 16), 16, 0, 0);
        }
        #pragma unroll
        for (int p = 0; p < 4; ++p) {
            int ci = p * 256 + tid, row = ci >> 3, pc = ci & 7;
            int lc = pc ^ (row & 7);
            int gr = m0 + row; if (gr >= n) gr = n - 1;
            const u16* g = Ab + (size_t)gr * K + kt * 64 + lc * 8;
            __builtin_amdgcn_global_load_lds((const AS1 u32*)g,
                                             (AS3 u32*)(smA[bf] + ci * 16), 16, 0, 0);
        }
    };

    f32x4 acc[4][4] = {};

    stage(0, 0);
    stage(1, 1);

    for (int kt = 0; kt < NKT; ++kt) {
        if (kt + 1 < NKT) { asm volatile("s_waitcnt vmcnt(8)" ::: "memory"); }
        else             { asm volatile("s_waitcnt vmcnt(0)" ::: "memory"); }
        __builtin_amdgcn_s_barrier();
        __builtin_amdgcn_sched_barrier(0);

        const char* pa = smA[kt & 1] + (wr * 64) * 128;
        const char* pb = smB[kt & 1] + (wc * 64) * 128;
        #pragma unroll
        for (int kk = 0; kk < 2; ++kk) {
            const int kb = kk * 64 + kq * 16;
            bf16x8 av[4], bv[4];
            #pragma unroll
            for (int i = 0; i < 4; ++i) {
                av[i] = *(const bf16x8*)(pa + (i * 16 + r16) * 128 + (kb ^ swz));
                bv[i] = *(const bf16x8*)(pb + (i * 16 + r16) * 128 + (kb ^ swz));
            }
            #pragma unroll
            for (int mi = 0; mi < 4; ++mi)
                #pragma unroll
                for (int ni = 0; ni < 4; ++ni)
                    acc[mi][ni] = __builtin_amdgcn_mfma_f32_16x16x32_bf16(
                        av[mi], bv[ni], acc[mi][ni], 0, 0, 0);
        }

        __builtin_amdgcn_sched_barrier(0);
        __builtin_amdgcn_s_barrier();
        __builtin_amdgcn_sched_barrier(0);
        if (kt + 2 < NKT) stage(kt & 1, kt + 2);
    }

    const int cbo = o0 + wc * 64;
    #pragma unroll
    for (int ni = 0; ni < 4; ++ni) {
        int col = cbo + ni * 16 + r16;
        float bb = bias[col];
        #pragma unroll
        for (int mi = 0; mi < 4; ++mi)
            #pragma unroll
            for (int r = 0; r < 4; ++r) {
                int gr = m0 + wr * 64 + mi * 16 + kq * 4 + r;
                if (gr < n) oF[(size_t)gr * Ototal + col] = acc[mi][ni][r] + bb;
            }
    }
}

// ---------------------------------------------------------------------------
// Fused fp32 -> bf16 conversion of x + all 9 weight matrices (one launch).
// Segments in 8-element groups.
#define XG  2400000      // 50000*384/8
#define W0G 24576        // 512*384/8 per matrix
#define W1G 32768        // 512*512/8 per matrix
#define WOG 24576        // 384*512/8
#define CVT_TOTAL (XG + 4*W0G + 4*W1G + WOG)

__global__ __launch_bounds__(256)
void cvt_all(const float* __restrict__ x,
             const float* q0w, const float* k0w, const float* v0w, const float* s0w,
             const float* q1w, const float* k1w, const float* v1w, const float* s1w,
             const float* ow,
             u16* __restrict__ Xb, u16* __restrict__ Wc0,
             u16* __restrict__ Wc1, u16* __restrict__ WcO)
{
    int i = blockIdx.x * 256 + threadIdx.x;
    if (i >= CVT_TOTAL) return;
    const float* s; u16* d; int g;
    if (i < XG) { s = x; d = Xb; g = i; }
    else {
        int j = i - XG;
        if (j < 4 * W0G) {
            int q = j / W0G; g = j - q * W0G;
            s = (q == 0 ? q0w : q == 1 ? k0w : q == 2 ? v0w : s0w);
            d = Wc0 + (size_t)q * W0G * 8;
        } else if ((j -= 4 * W0G) < 4 * W1G) {
            int q = j / W1G; g = j - q * W1G;
            s = (q == 0 ? q1w : q == 1 ? k1w : q == 2 ? v1w : s1w);
            d = Wc1 + (size_t)q * W1G * 8;
        } else { j -= 4 * W1G; s = ow; d = WcO; g = j; }
    }
    float4 f0 = ((const float4*)s)[(size_t)g * 2];
    float4 f1 = ((const float4*)s)[(size_t)g * 2 + 1];
    uint4 o;
    o.x = pack2(f0.x, f0.y); o.y = pack2(f0.z, f0.w);
    o.z = pack2(f1.x, f1.y); o.w = pack2(f1.z, f1.w);
    ((uint4*)d)[g] = o;
}

// bias arena: [0..2047]=layer0 qkvs, [2048..4095]=layer1 qkvs, [4096..4479]=out
__global__ __launch_bounds__(256)
void pack_bias(const float* q0, const float* k0, const float* v0, const float* s0,
               const float* q1, const float* k1, const float* v1, const float* s1,
               const float* ob, float* __restrict__ dst)
{
    int i = blockIdx.x * 256 + threadIdx.x;
    if (i >= 4480) return;
    float v;
    if (i < 2048) {
        int j = i & 511, q = i >> 9;
        v = (q == 0 ? q0 : q == 1 ? k0 : q == 2 ? v0 : s0)[j];
    } else if (i < 4096) {
        int j = i - 2048; int q = j >> 9; j &= 511;
        v = (q == 0 ? q1 : q == 1 ? k1 : q == 2 ? v1 : s1)[j];
    } else {
        v = ob[i - 4096];
    }
    dst[i] = v;
}

// ---------------------------------------------------------------------------
// CSR build (order within bucket nondeterministic -> only permutes fp adds)
// ---------------------------------------------------------------------------
__global__ __launch_bounds__(256)
void zero_deg(int* __restrict__ deg)
{
    int i = blockIdx.x * 256 + threadIdx.x;
    if (i < NN) deg[i] = 0;
}

__global__ __launch_bounds__(256)
void hist_dst(const int* __restrict__ dst, int* __restrict__ deg)
{
    int e = blockIdx.x * 256 + threadIdx.x;
    if (e < NE) atomicAdd(&deg[dst[e]], 1);
}

// single-block scan, wave-shfl based: 3 barriers per 1024-chunk (was 20)
__global__ __launch_bounds__(1024)
void scan_deg(const int* __restrict__ deg, int* __restrict__ rowptr,
              int* __restrict__ cursor)
{
    __shared__ int wsum[16];
    const int tid = threadIdx.x, lane = tid & 63, wid = tid >> 6;
    int carry = 0;
    for (int base = 0; base < NN; base += 1024) {
        int i = base + tid;
        int orig = (i < NN) ? deg[i] : 0;
        int v = orig;
        #pragma unroll
        for (int off = 1; off < 64; off <<= 1) {
            int t = __shfl_up(v, off, 64);
            if (lane >= off) v += t;
        }
        if (lane == 63) wsum[wid] = v;
        __syncthreads();
        if (wid == 0) {
            int s = (lane < 16) ? wsum[lane] : 0;
            #pragma unroll
            for (int off = 1; off < 16; off <<= 1) {
                int t = __shfl_up(s, off, 16);
                if ((lane & 15) >= off) s += t;
            }
            if (lane < 16) wsum[lane] = s;   // inclusive wave-prefix
        }
        __syncthreads();
        int woff  = (wid == 0) ? 0 : wsum[wid - 1];
        int total = wsum[15];
        int excl  = carry + woff + (v - orig);
        if (i < NN) { rowptr[i] = excl; cursor[i] = excl; }
        carry += total;
        __syncthreads();                     // wsum reused next chunk
    }
    if (tid == 0) rowptr[NN] = NE;
}

__global__ __launch_bounds__(256)
void scatter_edges(const int* __restrict__ src, const int* __restrict__ dst,
                   int* __restrict__ cursor, int* __restrict__ esrc_ord)
{
    int e = blockIdx.x * 256 + threadIdx.x;
    if (e >= NE) return;
    int pos = atomicAdd(&cursor[dst[e]], 1);
    esrc_ord[pos] = src[e];
}

// ---------------------------------------------------------------------------
// Fused per-node attention: one 64-lane wave per dst node; online softmax.
// Lane owns 8 contiguous channels; 16-lane group = one head.
// out = bf16(relu(agg + skip)), skip is bf16.
// ---------------------------------------------------------------------------
__global__ __launch_bounds__(256)
void node_attn(const u16* __restrict__ Qb, const u16* __restrict__ Kb,
               const u16* __restrict__ Vb, const int* __restrict__ rowptr,
               const int* __restrict__ esrc, const u16* __restrict__ skipb,
               u16* __restrict__ outb)
{
    int d = blockIdx.x * 4 + (threadIdx.x >> 6);
    if (d >= NN) return;
    int lane = threadIdx.x & 63;

    uint4 qv = *((const uint4*)(Qb + (size_t)d * HC) + lane);
    float q[8] = { bflo(qv.x), bfhi(qv.x), bflo(qv.y), bfhi(qv.y),
                   bflo(qv.z), bfhi(qv.z), bflo(qv.w), bfhi(qv.w) };

    int beg = rowptr[d], end = rowptr[d + 1];
    float m = -INFINITY, den = 0.f;
    float acc[8] = {};

    for (int i = beg; i < end; ++i) {
        int s = esrc[i];
        uint4 kv = *((const uint4*)(Kb + (size_t)s * HC) + lane);
        float sum = q[0] * bflo(kv.x) + q[1] * bfhi(kv.x)
                  + q[2] * bflo(kv.y) + q[3] * bfhi(kv.y)
                  + q[4] * bflo(kv.z) + q[5] * bfhi(kv.z)
                  + q[6] * bflo(kv.w) + q[7] * bfhi(kv.w);
        #pragma unroll
        for (int off = 1; off < 16; off <<= 1) sum += __shfl_xor(sum, off, 64);
        float alpha = sum * 0.08838834764831845f;

        float mnew  = fmaxf(m, alpha);
        float scale = __expf(m - mnew);      // first edge: exp(-inf)=0
        float p     = __expf(alpha - mnew);
        den = den * scale + p;

        uint4 vv = *((const uint4*)(Vb + (size_t)s * HC) + lane);
        acc[0] = acc[0] * scale + p * bflo(vv.x);
        acc[1] = acc[1] * scale + p * bfhi(vv.x);
        acc[2] = acc[2] * scale + p * bflo(vv.y);
        acc[3] = acc[3] * scale + p * bfhi(vv.y);
        acc[4] = acc[4] * scale + p * bflo(vv.z);
        acc[5] = acc[5] * scale + p * bfhi(vv.z);
        acc[6] = acc[6] * scale + p * bflo(vv.w);
        acc[7] = acc[7] * scale + p * bfhi(vv.w);
        m = mnew;
    }

    float inv = 1.f / (den + 1e-16f);
    size_t base = (size_t)d * HC + lane * 8;
    uint4 sv = *((const uint4*)(skipb + base));
    float sk[8] = { bflo(sv.x), bfhi(sv.x), bflo(sv.y), bfhi(sv.y),
                    bflo(sv.z), bfhi(sv.z), bflo(sv.w), bfhi(sv.w) };
    uint4 o;
    o.x = pack2(fmaxf(acc[0] * inv + sk[0], 0.f), fmaxf(acc[1] * inv + sk[1], 0.f));
    o.y = pack2(fmaxf(acc[2] * inv + sk[2], 0.f), fmaxf(acc[3] * inv + sk[3], 0.f));
    o.z = pack2(fmaxf(acc[4] * inv + sk[4], 0.f), fmaxf(acc[5] * inv + sk[5], 0.f));
    o.w = pack2(fmaxf(acc[6] * inv + sk[6], 0.f), fmaxf(acc[7] * inv + sk[7], 0.f));
    *(uint4*)(outb + base) = o;
}

// ---------------------------------------------------------------------------
extern "C" void kernel_launch(void* const* d_in, const int* in_sizes, int n_in,
                              void* d_out, int out_size, void* d_ws, size_t ws_size,
                              hipStream_t stream)
{
    const float* x   = (const float*)d_in[0];
    const int* ei    = (const int*)d_in[1];
    const int* esrc  = ei;
    const int* edst  = ei + NE;
    const float* q0w = (const float*)d_in[2];  const float* q0b = (const float*)d_in[3];
    const float* k0w = (const float*)d_in[4];  const float* k0b = (const float*)d_in[5];
    const float* v0w = (const float*)d_in[6];  const float* v0b = (const float*)d_in[7];
    const float* s0w = (const float*)d_in[8];  const float* s0b = (const float*)d_in[9];
    const float* q1w = (const float*)d_in[10]; const float* q1b = (const float*)d_in[11];
    const float* k1w = (const float*)d_in[12]; const float* k1b = (const float*)d_in[13];
    const float* v1w = (const float*)d_in[14]; const float* v1b = (const float*)d_in[15];
    const float* s1w = (const float*)d_in[16]; const float* s1b = (const float*)d_in[17];
    const float* ow  = (const float*)d_in[18]; const float* obs = (const float*)d_in[19];

    // ---- workspace (~247 MB) ----
    char* p = (char*)d_ws;
    auto take = [&](size_t bytes) { void* r = (void*)p; p += (bytes + 255) & ~(size_t)255; return r; };
    u16*   Qb     = (u16*)take((size_t)NN * HC * 2);       // 51.2 MB
    u16*   Vb     = (u16*)take((size_t)NN * HC * 2);       // 51.2 MB
    u16*   Hb     = (u16*)take((size_t)NN * HC * 2);       // 51.2 MB
    u16*   Sb     = (u16*)take((size_t)NN * HC * 2);       // 51.2 MB (bf16 skip)
    u16*   Xb     = (u16*)take((size_t)NN * DD * 2);       // 38.4 MB (bf16 x)
    u16*   Wc0    = (u16*)take((size_t)2048 * DD * 2);     // 1.57 MB
    u16*   Wc1    = (u16*)take((size_t)2048 * HC * 2);     // 2.10 MB
    u16*   WcO    = (u16*)take((size_t)DD * HC * 2);       // 0.39 MB
    float* barena = (float*)take(4480 * 4);                // 17.9 KB

    // ---- scratch carved from d_out (dead before final GEMM overwrites all) ----
    char* dob = (char*)d_out;
    u16* Kb       = (u16*)dob;                             // 51.2 MB
    int* deg      = (int*)(dob + 51200000);
    int* rowptr   = (int*)(dob + 51400192);                // NN+1
    int* cursor   = (int*)(dob + 51600384);
    int* esrc_ord = (int*)(dob + 51800576);                // 1.6 MB

    dim3 blk(256);
    int gN   = (NN + 255) / 256;
    int gE   = (NE + 255) / 256;
    int gnod = (NN + 3) / 4;
    const int NPAN = (NN + 127) / 128;   // 391 row panels
    int go = NPAN * 3;                   // out-proj: 3 col-tiles

    // ---- prep (2 launches) ----
    pack_bias<<<(4480 + 255) / 256, blk, 0, stream>>>(q0b, k0b, v0b, s0b,
                                                      q1b, k1b, v1b, s1b, obs, barena);
    cvt_all<<<(CVT_TOTAL + 255) / 256, blk, 0, stream>>>(x,
        q0w, k0w, v0w, s0w, q1w, k1w, v1w, s1w, ow, Xb, Wc0, Wc1, WcO);

    // ---- CSR build ----
    zero_deg      <<<gN, blk, 0, stream>>>(deg);
    hist_dst      <<<gE, blk, 0, stream>>>(edst, deg);
    scan_deg      <<<1, 1024, 0, stream>>>(deg, rowptr, cursor);
    scatter_edges <<<gE, blk, 0, stream>>>(esrc, edst, cursor, esrc_ord);

    // ---- layer 0 (A = Xb bf16, K=384) ----
    gemm_ws<DD><<<256, 512, 0, stream>>>(Xb, Wc0, barena, Qb, Kb, Vb, Sb);
    node_attn<<<gnod, blk, 0, stream>>>(Qb, Kb, Vb, rowptr, esrc_ord, Sb, Hb);

    // ---- layer 1 (A = Hb bf16, K=512) ----
    gemm_ws<HC><<<256, 512, 0, stream>>>(Hb, Wc1, barena + 2048, Qb, Kb, Vb, Sb);
    node_attn<<<gnod, blk, 0, stream>>>(Qb, Kb, Vb, rowptr, esrc_ord, Sb, Hb);

    // ---- output projection (fp32 out, overwrites ALL of d_out) ----
    gemm2ph<HC><<<go, blk, 0, stream>>>(Hb, WcO, barena + 4096,
                                        (float*)d_out, NN, 384, 3);
}